// Round 1
// baseline (197.069 us; speedup 1.0000x reference)
//
#include <hip/hip_runtime.h>

// Embedding row gather: out[s, :] = weights[x[s], :]
// x: [1, 8192] int32, weights: [49408, 768] fp32, out: [8192, 768] fp32.
// One 64-lane wave per row; 768 floats = 192 float4 -> 3 float4 per lane.
// 4 rows (waves) per 256-thread block -> 2048 blocks.

#define SEQ 8192
#define DIM 768
#define F4_PER_ROW (DIM / 4)   // 192

__global__ __launch_bounds__(256) void embed_gather(
    const int* __restrict__ ids,
    const float4* __restrict__ w,     // weights viewed as float4
    float4* __restrict__ out)         // output viewed as float4
{
    const int wave = threadIdx.x >> 6;          // 0..3
    const int lane = threadIdx.x & 63;
    const int row  = blockIdx.x * 4 + wave;     // 0..8191
    // All 64 lanes load the same address -> broadcast, cheap.
    const int tok = ids[row];

    const float4* __restrict__ src = w   + (size_t)tok * F4_PER_ROW;
    float4* __restrict__       dst = out + (size_t)row * F4_PER_ROW;

    // 192 float4 per row, 64 lanes -> 3 per lane, stride-64 keeps coalescing.
    float4 a = src[lane];
    float4 b = src[lane + 64];
    float4 c = src[lane + 128];
    dst[lane]       = a;
    dst[lane + 64]  = b;
    dst[lane + 128] = c;
}

extern "C" void kernel_launch(void* const* d_in, const int* in_sizes, int n_in,
                              void* d_out, int out_size, void* d_ws, size_t ws_size,
                              hipStream_t stream) {
    const int*    ids = (const int*)d_in[0];
    const float4* w   = (const float4*)d_in[1];
    float4*       out = (float4*)d_out;

    dim3 grid(SEQ / 4);   // 2048 blocks, 4 rows per block
    dim3 block(256);
    embed_gather<<<grid, block, 0, stream>>>(ids, w, out);
}

// Round 3
// 196.374 us; speedup vs baseline: 1.0035x; 1.0035x over previous
//
#include <hip/hip_runtime.h>

// Embedding row gather: out[s, :] = weights[x[s], :]
// x: [1, 8192] int32, weights: [49408, 768] fp32, out: [8192, 768] fp32.
// One 64-lane wave per row; 768 floats = 192 float4 -> 3 float4 per lane.
// 4 rows (waves) per 256-thread block -> 2048 blocks.
// Stores are nontemporal: output is write-once, keep L2/L3 clean so the
// 151 MB weights table stays L3-resident for the gather reads.
// NOTE: __builtin_nontemporal_store requires a native vector type, not
// HIP's struct float4 -> use clang ext_vector_type(4).

#define SEQ 8192
#define DIM 768
#define F4_PER_ROW (DIM / 4)   // 192

typedef float vfloat4 __attribute__((ext_vector_type(4)));

__global__ __launch_bounds__(256) void embed_gather(
    const int* __restrict__ ids,
    const vfloat4* __restrict__ w,     // weights viewed as float4
    vfloat4* __restrict__ out)         // output viewed as float4
{
    const int wave = threadIdx.x >> 6;          // 0..3
    const int lane = threadIdx.x & 63;
    const int row  = blockIdx.x * 4 + wave;     // 0..8191
    // All 64 lanes load the same address -> broadcast, cheap.
    const int tok = ids[row];

    const vfloat4* __restrict__ src = w   + (size_t)tok * F4_PER_ROW;
    vfloat4* __restrict__       dst = out + (size_t)row * F4_PER_ROW;

    // 192 float4 per row, 64 lanes -> 3 per lane, stride-64 keeps coalescing.
    vfloat4 a = src[lane];
    vfloat4 b = src[lane + 64];
    vfloat4 c = src[lane + 128];
    __builtin_nontemporal_store(a, dst + lane);
    __builtin_nontemporal_store(b, dst + lane + 64);
    __builtin_nontemporal_store(c, dst + lane + 128);
}

extern "C" void kernel_launch(void* const* d_in, const int* in_sizes, int n_in,
                              void* d_out, int out_size, void* d_ws, size_t ws_size,
                              hipStream_t stream) {
    const int*     ids = (const int*)d_in[0];
    const vfloat4* w   = (const vfloat4*)d_in[1];
    vfloat4*       out = (vfloat4*)d_out;

    dim3 grid(SEQ / 4);   // 2048 blocks, 4 rows per block
    dim3 block(256);
    embed_gather<<<grid, block, 0, stream>>>(ids, w, out);
}